// Round 7
// baseline (483.137 us; speedup 1.0000x reference)
//
#include <hip/hip_runtime.h>

typedef unsigned int u32;
typedef _Float16 f16;
typedef f16 h2 __attribute__((ext_vector_type(2)));

// ---------------- packed-weight ws layout (u32/f32 element offsets) ----------
#define QP     0        // [e<32][i<8] half2 pairs over f           (256)
#define KVP    256      // [e<64][i<8]                              (512)
#define WOP    768      // [f<16][i<16] pairs over e                (256)
#define ILWP   1024     // [(jp4<64 *32 + t)*4 + i] pairs over j    (8192)
#define WIHP   9216     // [(kp<16 *32 + t)*4 + j] j<3 used         (2048)
#define WHHP   11264    //                                          (2048)
#define MSWP   13312    // [kp<16 *32 + t]                          (512)
#define MGWP   13824    // [a*512 + kp<16 *32 + m]                  (32768)
#define QSWP   46592    // [kp<32 *32 + t]                          (1024)
#define AHWP   47616    // [a*256 + kp<16 *16 + u]                  (16384)
#define F32B   64000
#define BQ     (F32B+0)     // 32
#define BKV    (F32B+32)    // 64
#define BO     (F32B+96)    // 16
#define LN1G   (F32B+112)   // 16
#define LN1B   (F32B+128)   // 16
#define ILB    (F32B+144)   // 32
#define BIH    (F32B+176)   // 96
#define BHH    (F32B+272)   // 96
#define MSB    (F32B+368)   // 32
#define MGB    (F32B+400)   // 2048
#define MAWKVV (F32B+2448)  // 1024  wkv_V as [k<32][t<32]
#define MABKVV (F32B+3472)  // 32
#define MAWO   (F32B+3504)  // 1024
#define MABO   (F32B+4528)  // 32
#define LN2G   (F32B+4560)  // 32
#define LN2B   (F32B+4592)  // 32
#define QSB    (F32B+4624)  // 32
#define AHB    (F32B+4656)  // 1024
#define W_TOTAL (F32B+5680)
#define W_ALLOC 69696
#define MSUM_N  32768       // 1024 batches x 32, f32, after W in ws

// output element offsets (f32): q_values | h | mean_message
#define OUT_Q  0
#define OUT_H  1048576
#define OUT_MM 3145728

#if __has_builtin(__builtin_amdgcn_fdot2)
__device__ __forceinline__ float FD(h2 a, h2 b, float c) {
    return __builtin_amdgcn_fdot2(a, b, c, false);
}
#else
__device__ __forceinline__ float FD(h2 a, h2 b, float c) {
    return c + (float)a.x * (float)b.x + (float)a.y * (float)b.y;
}
#endif

#if __has_builtin(__builtin_amdgcn_cvt_pkrtz)
__device__ __forceinline__ h2 pk2(float a, float b) {
    auto r = __builtin_amdgcn_cvt_pkrtz(a, b);   // __fp16 vec2 on this clang
    h2 out;
    __builtin_memcpy(&out, &r, sizeof(out));      // no-op bitcast
    return out;
}
#else
__device__ __forceinline__ h2 pk2(float a, float b) { h2 r; r.x = (f16)a; r.y = (f16)b; return r; }
#endif

__device__ __forceinline__ h2  u2h(u32 x) { union { u32 u; h2 h; } c; c.u = x; return c.h; }
__device__ __forceinline__ u32 h2u(h2 x)  { union { u32 u; h2 h; } c; c.h = x; return c.u; }

__device__ __forceinline__ float sigm(float x) { return 1.0f / (1.0f + __expf(-x)); }

struct WP { const float* p[30]; };

// K0: repack weights (f16 pairs along contraction dim) + f32 tail + zero msum
__global__ void kw_conv(WP wp, float* W, float* msum) {
    u32* Wu = (u32*)W;
    int gid = blockIdx.x * blockDim.x + threadIdx.x;
    if (gid < MSUM_N) msum[gid] = 0.0f;
    if (gid >= W_TOTAL) return;
    if (gid < KVP) {                       // QP: ia_wq [16][32]
        int e = gid >> 3, i = gid & 7;
        const float* wq = wp.p[0];
        Wu[gid] = h2u(pk2(wq[(2*i)*32 + e], wq[(2*i+1)*32 + e]));
    } else if (gid < WOP) {                // KVP: ia_wkv [16][64]
        int idx = gid - KVP; int e = idx >> 3, i = idx & 7;
        const float* wkv = wp.p[2];
        Wu[gid] = h2u(pk2(wkv[(2*i)*64 + e], wkv[(2*i+1)*64 + e]));
    } else if (gid < ILWP) {               // WOP: ia_wo [32][16]
        int idx = gid - WOP; int f = idx >> 4, i = idx & 15;
        const float* wo = wp.p[4];
        Wu[gid] = h2u(pk2(wo[(2*i)*16 + f], wo[(2*i+1)*16 + f]));
    } else if (gid < WIHP) {               // ILWP: il_w [512][32]
        int idx = gid - ILWP;
        int jp4 = idx >> 7, t = (idx >> 2) & 31, i = idx & 3;
        int jp = jp4 * 4 + i;
        const float* ilw = wp.p[8];
        Wu[gid] = h2u(pk2(ilw[(2*jp)*32 + t], ilw[(2*jp+1)*32 + t]));
    } else if (gid < WHHP) {               // WIHP: gru_wih [32][96]
        int idx = gid - WIHP;
        int kp = idx >> 7, t = (idx >> 2) & 31, j = idx & 3;
        const float* wih = wp.p[10];
        Wu[gid] = (j < 3) ? h2u(pk2(wih[(2*kp)*96 + j*32 + t], wih[(2*kp+1)*96 + j*32 + t])) : 0u;
    } else if (gid < MSWP) {               // WHHP: gru_whh [32][96]
        int idx = gid - WHHP;
        int kp = idx >> 7, t = (idx >> 2) & 31, j = idx & 3;
        const float* whh = wp.p[11];
        Wu[gid] = (j < 3) ? h2u(pk2(whh[(2*kp)*96 + j*32 + t], whh[(2*kp+1)*96 + j*32 + t])) : 0u;
    } else if (gid < MGWP) {               // MSWP: ms_w [32][32]
        int idx = gid - MSWP; int kp = idx >> 5, t = idx & 31;
        const float* msw = wp.p[14];
        Wu[gid] = h2u(pk2(msw[(2*kp)*32 + t], msw[(2*kp+1)*32 + t]));
    } else if (gid < QSWP) {               // MGWP: mg_w [64][32][32]
        int idx = gid - MGWP; int a = idx >> 9, rem = idx & 511, kp = rem >> 5, m = rem & 31;
        const float* mgw = wp.p[16];
        Wu[gid] = h2u(pk2(mgw[(a*32 + 2*kp)*32 + m], mgw[(a*32 + 2*kp+1)*32 + m]));
    } else if (gid < AHWP) {               // QSWP: qs_w [64][32]
        int idx = gid - QSWP; int kp = idx >> 5, t = idx & 31;
        const float* qsw = wp.p[26];
        Wu[gid] = h2u(pk2(qsw[(2*kp)*32 + t], qsw[(2*kp+1)*32 + t]));
    } else if (gid < F32B) {               // AHWP: ah_w [64][32][16]
        int idx = gid - AHWP; int a = idx >> 8, rem = idx & 255, kp = rem >> 4, u = rem & 15;
        const float* ahw = wp.p[28];
        Wu[gid] = h2u(pk2(ahw[(a*32 + 2*kp)*16 + u], ahw[(a*32 + 2*kp+1)*16 + u]));
    } else {                               // f32 tail
        int i = gid - F32B;
        float v;
        if      (i < 32)   v = wp.p[1][i];                 // bq
        else if (i < 96)   v = wp.p[3][i - 32];            // bkv
        else if (i < 112)  v = wp.p[5][i - 96];            // bo
        else if (i < 128)  v = wp.p[6][i - 112];           // ln1_g
        else if (i < 144)  v = wp.p[7][i - 128];           // ln1_b
        else if (i < 176)  v = wp.p[9][i - 144];           // il_b
        else if (i < 272)  v = wp.p[12][i - 176];          // gru_bih
        else if (i < 368)  v = wp.p[13][i - 272];          // gru_bhh
        else if (i < 400)  v = wp.p[15][i - 368];          // ms_b
        else if (i < 2448) v = wp.p[17][i - 400];          // mg_b
        else if (i < 3472) { int j = i - 2448; v = wp.p[20][(j >> 5)*64 + 32 + (j & 31)]; } // ma_wkv V
        else if (i < 3504) v = wp.p[21][32 + (i - 3472)];  // ma_bkv V
        else if (i < 4528) v = wp.p[22][i - 3504];         // ma_wo
        else if (i < 4560) v = wp.p[23][i - 4528];         // ma_bo
        else if (i < 4592) v = wp.p[24][i - 4560];         // ln2_g
        else if (i < 4624) v = wp.p[25][i - 4592];         // ln2_b
        else if (i < 4656) v = wp.p[27][i - 4624];         // qs_b
        else               v = wp.p[29][i - 4656];         // ah_b
        W[gid] = v;
    }
}

// K1: per wave = 2 agents. lane = (sub<<5)|t ; t = link/row index.
// LDS 36.8 KB -> 4 blocks/CU (LDS-limited). launch_bounds min 3 waves/EU so the
// allocator does NOT squeeze to 64 VGPR and spill (round-6 lesson: (256,4)
// spilled scf -> 208 MiB scratch traffic). K/V rows XOR-col-swizzled
// (compile-time offsets after unroll). aftH overlays KbH (dead after P2).
__global__ __launch_bounds__(256, 3) void k_main(
    const float* __restrict__ states, const float* __restrict__ hidden,
    const float* W, float* __restrict__ msum, float* __restrict__ outp)
{
    const u32* Wu = (const u32*)W;

    __shared__ uint4 KbH[8][32][4];   // f16 K rows (swizzled); later: aft rows
    __shared__ uint4 VbH[8][32][4];   // f16 V rows (swizzled)
    __shared__ __align__(16) float encS[8][32];
    __shared__ __align__(16) float hS[8][32];
    __shared__ __align__(16) float hnS[8][32];
    __shared__ __align__(16) float membS[8][32];

    const int w    = threadIdx.x >> 6;
    const int lane = threadIdx.x & 63;
    const int sub  = lane >> 5;
    const int t    = lane & 31;
    const int ag   = w * 2 + sub;
    const int pair = blockIdx.x * 4 + w;
    const int b    = pair >> 5;
    const int a    = ((pair & 31) << 1) | sub;
    const int ba   = b * 64 + a;

    // ---- P0: states row (link t): 16 f32; hidden value (latency overlap) ----
    float s[16];
    {
        const float4* p4 = reinterpret_cast<const float4*>(states + ((size_t)ba * 32 + t) * 16);
        float4 f0 = p4[0], f1 = p4[1], f2 = p4[2], f3 = p4[3];
        s[0]=f0.x; s[1]=f0.y; s[2]=f0.z; s[3]=f0.w;
        s[4]=f1.x; s[5]=f1.y; s[6]=f1.z; s[7]=f1.w;
        s[8]=f2.x; s[9]=f2.y; s[10]=f2.z; s[11]=f2.w;
        s[12]=f3.x; s[13]=f3.y; s[14]=f3.z; s[15]=f3.w;
    }
    float hp = hidden[(size_t)ba * 32 + t];
    h2 sh[8];
    #pragma unroll
    for (int i = 0; i < 8; ++i) sh[i] = pk2(s[2*i], s[2*i+1]);

    // ---- P1a: Q (packed pairs; weights wave-uniform -> s_load) ----
    h2 qh[16];
    #pragma unroll
    for (int j = 0; j < 16; ++j) {
        float a0 = W[BQ + 2*j], a1 = W[BQ + 2*j + 1];
        #pragma unroll
        for (int i = 0; i < 8; ++i) {
            a0 = FD(sh[i], u2h(Wu[QP + (2*j)*8 + i]), a0);
            a1 = FD(sh[i], u2h(Wu[QP + (2*j+1)*8 + i]), a1);
        }
        qh[j] = pk2(a0, a1);
    }
    // ---- P1b: K,V rows -> f16 LDS (swizzled cols) ----
    #pragma unroll
    for (int u = 0; u < 4; ++u) {
        u32 kc[4], vc[4];
        #pragma unroll
        for (int c = 0; c < 4; ++c) {
            int e0 = u*8 + 2*c, e1 = e0 + 1;
            float k0 = W[BKV+e0], k1 = W[BKV+e1];
            float v0 = W[BKV+32+e0], v1 = W[BKV+32+e1];
            #pragma unroll
            for (int i = 0; i < 8; ++i) {
                k0 = FD(sh[i], u2h(Wu[KVP + e0*8 + i]), k0);
                k1 = FD(sh[i], u2h(Wu[KVP + e1*8 + i]), k1);
                v0 = FD(sh[i], u2h(Wu[KVP + (32+e0)*8 + i]), v0);
                v1 = FD(sh[i], u2h(Wu[KVP + (32+e1)*8 + i]), v1);
            }
            kc[c] = h2u(pk2(k0, k1)); vc[c] = h2u(pk2(v0, v1));
        }
        int uc = u ^ (t & 3);
        KbH[ag][t][uc] = make_uint4(kc[0], kc[1], kc[2], kc[3]);
        VbH[ag][t][uc] = make_uint4(vc[0], vc[1], vc[2], vc[3]);
    }
    __syncthreads();

    // ---- P2: 4-head attention, single pass: ov += e*V, l += e; divide once.
    //          (no max-subtract: scores ~N(0,0.2), exp-safe; no scf array ->
    //           no register-file pressure / spill) ----
    h2 oh[16];
    const float scale = 0.35355339059327373f; // 1/sqrt(8)
    #pragma unroll
    for (int hh = 0; hh < 4; ++hh) {
        float l0 = 0.0f, l1 = 0.0f;
        h2 ov0 = {(f16)0, (f16)0}, ov1 = ov0, ov2 = ov0, ov3 = ov0;
        #pragma unroll
        for (int k = 0; k < 32; ++k) {
            uint4 kr = KbH[ag][k][hh ^ (k & 3)];   // uniform addr -> broadcast
            float sc = 0.0f;
            sc = FD(qh[hh*4+0], u2h(kr.x), sc);
            sc = FD(qh[hh*4+1], u2h(kr.y), sc);
            sc = FD(qh[hh*4+2], u2h(kr.z), sc);
            sc = FD(qh[hh*4+3], u2h(kr.w), sc);
            float e = __expf(sc * scale);
            if (k & 1) l1 += e; else l0 += e;
            h2 ph = pk2(e, e);
            uint4 vr = VbH[ag][k][hh ^ (k & 3)];
            ov0 += ph * u2h(vr.x);
            ov1 += ph * u2h(vr.y);
            ov2 += ph * u2h(vr.z);
            ov3 += ph * u2h(vr.w);
        }
        float inv = 1.0f / (l0 + l1);
        h2 hinv = pk2(inv, inv);
        oh[hh*4+0] = ov0 * hinv; oh[hh*4+1] = ov1 * hinv;
        oh[hh*4+2] = ov2 * hinv; oh[hh*4+3] = ov3 * hinv;
    }

    // ---- P3: out proj + residual + LayerNorm(16) ----
    float aft[16];
    {
        float x[16];
        float mean = 0.0f;
        #pragma unroll
        for (int f = 0; f < 16; ++f) {
            float acc = W[BO + f];
            #pragma unroll
            for (int i = 0; i < 16; ++i) acc = FD(oh[i], u2h(Wu[WOP + f*16 + i]), acc);
            x[f] = s[f] + acc;
            mean += x[f];
        }
        mean *= (1.0f / 16.0f);
        float var = 0.0f;
        #pragma unroll
        for (int f = 0; f < 16; ++f) { float d = x[f] - mean; var += d * d; }
        var *= (1.0f / 16.0f);
        float rs = rsqrtf(var + 1e-5f);
        #pragma unroll
        for (int f = 0; f < 16; ++f)
            aft[f] = (x[f] - mean) * rs * W[LN1G + f] + W[LN1B + f];
    }
    // aft rows -> LDS, overlaying KbH[ag] (dead after P2)
    uint4* aftA = &KbH[ag][0][0];   // 64 uint4 per ag-group
    {
        u32 ac[8];
        #pragma unroll
        for (int c = 0; c < 8; ++c) ac[c] = h2u(pk2(aft[2*c], aft[2*c+1]));
        aftA[2*t]     = make_uint4(ac[0], ac[1], ac[2], ac[3]);
        aftA[2*t + 1] = make_uint4(ac[4], ac[5], ac[6], ac[7]);
    }
    hS[ag][t] = hp;
    __syncthreads();

    // ---- P4: enc[t] = il_b[t] + aft_flat . il_w[:,t]  (f16 dot2) ----
    float enc = W[ILB + t];
    {
        const uint4* aA   = aftA;
        const uint4* ilw4 = (const uint4*)(Wu + ILWP);
        #pragma unroll 8
        for (int jp4 = 0; jp4 < 64; ++jp4) {
            uint4 av = aA[jp4];
            uint4 wv = ilw4[jp4 * 32 + t];
            enc = FD(u2h(av.x), u2h(wv.x), enc);
            enc = FD(u2h(av.y), u2h(wv.y), enc);
            enc = FD(u2h(av.z), u2h(wv.z), enc);
            enc = FD(u2h(av.w), u2h(wv.w), enc);
        }
    }
    encS[ag][t] = enc;
    __syncthreads();

    // ---- P5: GRU ----
    float gi0 = W[BIH + t], gi1 = W[BIH + 32 + t], gi2 = W[BIH + 64 + t];
    float gh0 = W[BHH + t], gh1 = W[BHH + 32 + t], gh2 = W[BHH + 64 + t];
    {
        const float4* eF = (const float4*)&encS[ag][0];
        const float4* hF = (const float4*)&hS[ag][0];
        const uint4* wi4 = (const uint4*)(Wu + WIHP);
        const uint4* wh4 = (const uint4*)(Wu + WHHP);
        #pragma unroll
        for (int q4 = 0; q4 < 8; ++q4) {
            float4 ev = eF[q4], hv = hF[q4];
            h2 ea = pk2(ev.x, ev.y), eb = pk2(ev.z, ev.w);
            h2 ha = pk2(hv.x, hv.y), hb = pk2(hv.z, hv.w);
            uint4 wiA = wi4[(q4*2)*32 + t], wiB = wi4[(q4*2+1)*32 + t];
            uint4 whA = wh4[(q4*2)*32 + t], whB = wh4[(q4*2+1)*32 + t];
            gi0 = FD(ea, u2h(wiA.x), gi0); gi1 = FD(ea, u2h(wiA.y), gi1); gi2 = FD(ea, u2h(wiA.z), gi2);
            gi0 = FD(eb, u2h(wiB.x), gi0); gi1 = FD(eb, u2h(wiB.y), gi1); gi2 = FD(eb, u2h(wiB.z), gi2);
            gh0 = FD(ha, u2h(whA.x), gh0); gh1 = FD(ha, u2h(whA.y), gh1); gh2 = FD(ha, u2h(whA.z), gh2);
            gh0 = FD(hb, u2h(whB.x), gh0); gh1 = FD(hb, u2h(whB.y), gh1); gh2 = FD(hb, u2h(whB.z), gh2);
        }
    }
    float r  = sigm(gi0 + gh0);
    float z  = sigm(gi1 + gh1);
    float n  = tanhf(gi2 + r * gh2);
    float hn = (1.0f - z) * n + z * hp;
    outp[OUT_H + (size_t)ba * 32 + t] = hn;
    hnS[ag][t] = hn;
    __syncthreads();

    // ---- P6: memb = relu(h @ ms_w + b); msg = memb @ mg_w[a] + b;
    //          accumulate batch-mean numerator via device atomics ----
    {
        const float4* nF = (const float4*)&hnS[ag][0];
        float mb = W[MSB + t];
        #pragma unroll
        for (int q4 = 0; q4 < 8; ++q4) {
            float4 v = nF[q4];
            h2 a2 = pk2(v.x, v.y), b2 = pk2(v.z, v.w);
            mb = FD(a2, u2h(Wu[MSWP + (q4*2)*32 + t]), mb);
            mb = FD(b2, u2h(Wu[MSWP + (q4*2+1)*32 + t]), mb);
        }
        mb = fmaxf(mb, 0.0f);
        membS[ag][t] = mb;
    }
    __syncthreads();
    {
        const float4* mF = (const float4*)&membS[ag][0];
        float mg = W[MGB + a * 32 + t];
        #pragma unroll
        for (int q4 = 0; q4 < 8; ++q4) {
            float4 v = mF[q4];
            h2 a2 = pk2(v.x, v.y), b2 = pk2(v.z, v.w);
            mg = FD(a2, u2h(Wu[MGWP + a*512 + (q4*2)*32 + t]), mg);
            mg = FD(b2, u2h(Wu[MGWP + a*512 + (q4*2+1)*32 + t]), mg);
        }
        atomicAdd(&msum[b * 32 + t], mg);
    }
}

// K2: mm = msum/64 -> write OUT_MM broadcast; inline degenerate comm-attn
// (sl=1 => softmax==1 => ao = (mm @ wkv_V + bkv_V) @ wo + bo, per batch);
// LN2(h+ao) -> feat=[h,after] -> relu(qs) -> per-agent Q head.
__global__ __launch_bounds__(256) void k_tail(
    const float* __restrict__ msum, const float* W, float* __restrict__ outp)
{
    const u32* Wu = (const u32*)W;
    __shared__ __align__(16) float mmS[8][32];
    __shared__ __align__(16) float vS[8][32];
    __shared__ __align__(16) float featS[8][64];
    __shared__ __align__(16) float qeS[8][32];
    const int w    = threadIdx.x >> 6;
    const int lane = threadIdx.x & 63;
    const int sub  = lane >> 5;
    const int t    = lane & 31;
    const int ag   = w * 2 + sub;
    const int pair = blockIdx.x * 4 + w;
    const int b    = pair >> 5;
    const int a    = ((pair & 31) << 1) | sub;
    const int ba   = b * 64 + a;

    float h  = outp[OUT_H + (size_t)ba * 32 + t];
    float mm = msum[b * 32 + t] * 0.015625f;    // /64
    outp[OUT_MM + (size_t)ba * 32 + t] = mm;
    mmS[ag][t] = mm;
    __syncthreads();
    float v = W[MABKVV + t];
    for (int k = 0; k < 32; ++k) v += mmS[ag][k] * W[MAWKVV + k * 32 + t];
    vS[ag][t] = v;
    __syncthreads();
    float ao = W[MABO + t];
    for (int k = 0; k < 32; ++k) ao += vS[ag][k] * W[MAWO + k * 32 + t];

    float x  = h + ao;
    float sm = x;
    #pragma unroll
    for (int m2 = 1; m2 < 32; m2 <<= 1) sm += __shfl_xor(sm, m2, 64);
    float mean = sm * (1.0f / 32.0f);
    float dx = x - mean;
    float vv = dx * dx;
    #pragma unroll
    for (int m2 = 1; m2 < 32; m2 <<= 1) vv += __shfl_xor(vv, m2, 64);
    float var   = vv * (1.0f / 32.0f);
    float after = dx * rsqrtf(var + 1e-5f) * W[LN2G + t] + W[LN2B + t];

    featS[ag][t]      = h;
    featS[ag][32 + t] = after;
    __syncthreads();
    {
        const float4* fF = (const float4*)&featS[ag][0];
        float acc = W[QSB + t];
        #pragma unroll
        for (int q4 = 0; q4 < 16; ++q4) {
            float4 fv = fF[q4];
            h2 a2 = pk2(fv.x, fv.y), b2 = pk2(fv.z, fv.w);
            acc = FD(a2, u2h(Wu[QSWP + (q4*2)*32 + t]), acc);
            acc = FD(b2, u2h(Wu[QSWP + (q4*2+1)*32 + t]), acc);
        }
        acc = fmaxf(acc, 0.0f);
        qeS[ag][t] = acc;
    }
    __syncthreads();
    if (t < 16) {
        const float4* qF = (const float4*)&qeS[ag][0];
        float qa = W[AHB + a * 16 + t];
        #pragma unroll
        for (int q4 = 0; q4 < 8; ++q4) {
            float4 qv = qF[q4];
            h2 a2 = pk2(qv.x, qv.y), b2 = pk2(qv.z, qv.w);
            qa = FD(a2, u2h(Wu[AHWP + a*256 + (q4*2)*16 + t]), qa);
            qa = FD(b2, u2h(Wu[AHWP + a*256 + (q4*2+1)*16 + t]), qa);
        }
        outp[OUT_Q + (size_t)ba * 16 + t] = qa;
    }
}

extern "C" void kernel_launch(void* const* d_in, const int* in_sizes, int n_in,
                              void* d_out, int out_size, void* d_ws, size_t ws_size,
                              hipStream_t stream) {
    (void)in_sizes; (void)n_in; (void)out_size; (void)ws_size;
    WP wp;
    for (int i = 0; i < 30; ++i) wp.p[i] = (const float*)d_in[i + 2];

    float* W    = (float*)d_ws;
    float* msum = W + W_ALLOC;   // 1024*32 f32, zeroed by kw_conv each call

    const float* states = (const float*)d_in[0];
    const float* hidden = (const float*)d_in[1];
    float* outp = (float*)d_out;

    kw_conv<<<dim3((W_TOTAL + 255) / 256), dim3(256), 0, stream>>>(wp, W, msum);
    k_main<<<dim3(8192), dim3(256), 0, stream>>>(states, hidden, W, msum, outp);
    k_tail<<<dim3(8192), dim3(256), 0, stream>>>(msum, W, outp);
}

// Round 8
// 482.523 us; speedup vs baseline: 1.0013x; 1.0013x over previous
//
#include <hip/hip_runtime.h>

typedef unsigned int u32;
typedef _Float16 f16;
typedef f16 h2 __attribute__((ext_vector_type(2)));

// ---------------- packed-weight ws layout (u32/f32 element offsets) ----------
#define QP     0        // [e<32][i<8] half2 pairs over f, PRE-SCALED by 1/sqrt(8)*log2e
#define KVP    256      // [e<64][i<8]
#define WOP    768      // [f<16][i<16] pairs over e
#define ILWP   1024     // [(jp4<64 *32 + t)*4 + i] pairs over j
#define WIHP   9216     // [(kp<16 *32 + t)*4 + j] j<3 used
#define WHHP   11264
#define MSWP   13312    // [kp<16 *32 + t]
#define MGWP   13824    // [a*512 + kp<16 *32 + m]
#define QSWP   46592    // [kp<32 *32 + t]
#define AHWP   47616    // [a*256 + kp<16 *16 + u]
#define F32B   64000
#define BQ     (F32B+0)     // 32  (PRE-SCALED like QP)
#define BKV    (F32B+32)    // 64
#define BO     (F32B+96)    // 16
#define LN1G   (F32B+112)   // 16
#define LN1B   (F32B+128)   // 16
#define ILB    (F32B+144)   // 32
#define BIH    (F32B+176)   // 96
#define BHH    (F32B+272)   // 96
#define MSB    (F32B+368)   // 32
#define MGB    (F32B+400)   // 2048
#define MAWKVV (F32B+2448)  // 1024  wkv_V as [k<32][t<32]
#define MABKVV (F32B+3472)  // 32
#define MAWO   (F32B+3504)  // 1024
#define MABO   (F32B+4528)  // 32
#define LN2G   (F32B+4560)  // 32
#define LN2B   (F32B+4592)  // 32
#define QSB    (F32B+4624)  // 32
#define AHB    (F32B+4656)  // 1024
#define W_TOTAL (F32B+5680)
#define W_ALLOC 69696
#define MSUM_N  32768       // 1024 batches x 32, f32, after W in ws

// Q pre-scale: (1/sqrt(8)) * log2(e)  ->  exp(sc*scale) == exp2(sc')
#define QSCL 0.51006973f

// output element offsets (f32): q_values | h | mean_message
#define OUT_Q  0
#define OUT_H  1048576
#define OUT_MM 3145728

#if __has_builtin(__builtin_amdgcn_fdot2)
__device__ __forceinline__ float FD(h2 a, h2 b, float c) {
    return __builtin_amdgcn_fdot2(a, b, c, false);
}
#else
__device__ __forceinline__ float FD(h2 a, h2 b, float c) {
    return c + (float)a.x * (float)b.x + (float)a.y * (float)b.y;
}
#endif

#if __has_builtin(__builtin_amdgcn_exp2f)
__device__ __forceinline__ float EXP2(float x) { return __builtin_amdgcn_exp2f(x); }
#else
__device__ __forceinline__ float EXP2(float x) { return exp2f(x); }
#endif

#if __has_builtin(__builtin_amdgcn_cvt_pkrtz)
__device__ __forceinline__ h2 pk2(float a, float b) {
    auto r = __builtin_amdgcn_cvt_pkrtz(a, b);   // __fp16 vec2 on this clang
    h2 out;
    __builtin_memcpy(&out, &r, sizeof(out));      // no-op bitcast
    return out;
}
#else
__device__ __forceinline__ h2 pk2(float a, float b) { h2 r; r.x = (f16)a; r.y = (f16)b; return r; }
#endif

__device__ __forceinline__ h2  u2h(u32 x) { union { u32 u; h2 h; } c; c.u = x; return c.h; }
__device__ __forceinline__ u32 h2u(h2 x)  { union { u32 u; h2 h; } c; c.h = x; return c.u; }

__device__ __forceinline__ float sigm(float x) { return 1.0f / (1.0f + __expf(-x)); }

struct WP { const float* p[30]; };

// K0: repack weights (f16 pairs along contraction dim) + f32 tail + zero msum
__global__ void kw_conv(WP wp, float* W, float* msum) {
    u32* Wu = (u32*)W;
    int gid = blockIdx.x * blockDim.x + threadIdx.x;
    if (gid < MSUM_N) msum[gid] = 0.0f;
    if (gid >= W_TOTAL) return;
    if (gid < KVP) {                       // QP: ia_wq [16][32], pre-scaled
        int e = gid >> 3, i = gid & 7;
        const float* wq = wp.p[0];
        Wu[gid] = h2u(pk2(wq[(2*i)*32 + e] * QSCL, wq[(2*i+1)*32 + e] * QSCL));
    } else if (gid < WOP) {                // KVP: ia_wkv [16][64]
        int idx = gid - KVP; int e = idx >> 3, i = idx & 7;
        const float* wkv = wp.p[2];
        Wu[gid] = h2u(pk2(wkv[(2*i)*64 + e], wkv[(2*i+1)*64 + e]));
    } else if (gid < ILWP) {               // WOP: ia_wo [32][16]
        int idx = gid - WOP; int f = idx >> 4, i = idx & 15;
        const float* wo = wp.p[4];
        Wu[gid] = h2u(pk2(wo[(2*i)*16 + f], wo[(2*i+1)*16 + f]));
    } else if (gid < WIHP) {               // ILWP: il_w [512][32]
        int idx = gid - ILWP;
        int jp4 = idx >> 7, t = (idx >> 2) & 31, i = idx & 3;
        int jp = jp4 * 4 + i;
        const float* ilw = wp.p[8];
        Wu[gid] = h2u(pk2(ilw[(2*jp)*32 + t], ilw[(2*jp+1)*32 + t]));
    } else if (gid < WHHP) {               // WIHP: gru_wih [32][96]
        int idx = gid - WIHP;
        int kp = idx >> 7, t = (idx >> 2) & 31, j = idx & 3;
        const float* wih = wp.p[10];
        Wu[gid] = (j < 3) ? h2u(pk2(wih[(2*kp)*96 + j*32 + t], wih[(2*kp+1)*96 + j*32 + t])) : 0u;
    } else if (gid < MSWP) {               // WHHP: gru_whh [32][96]
        int idx = gid - WHHP;
        int kp = idx >> 7, t = (idx >> 2) & 31, j = idx & 3;
        const float* whh = wp.p[11];
        Wu[gid] = (j < 3) ? h2u(pk2(whh[(2*kp)*96 + j*32 + t], whh[(2*kp+1)*96 + j*32 + t])) : 0u;
    } else if (gid < MGWP) {               // MSWP: ms_w [32][32]
        int idx = gid - MSWP; int kp = idx >> 5, t = idx & 31;
        const float* msw = wp.p[14];
        Wu[gid] = h2u(pk2(msw[(2*kp)*32 + t], msw[(2*kp+1)*32 + t]));
    } else if (gid < QSWP) {               // MGWP: mg_w [64][32][32]
        int idx = gid - MGWP; int a = idx >> 9, rem = idx & 511, kp = rem >> 5, m = rem & 31;
        const float* mgw = wp.p[16];
        Wu[gid] = h2u(pk2(mgw[(a*32 + 2*kp)*32 + m], mgw[(a*32 + 2*kp+1)*32 + m]));
    } else if (gid < AHWP) {               // QSWP: qs_w [64][32]
        int idx = gid - QSWP; int kp = idx >> 5, t = idx & 31;
        const float* qsw = wp.p[26];
        Wu[gid] = h2u(pk2(qsw[(2*kp)*32 + t], qsw[(2*kp+1)*32 + t]));
    } else if (gid < F32B) {               // AHWP: ah_w [64][32][16]
        int idx = gid - AHWP; int a = idx >> 8, rem = idx & 255, kp = rem >> 4, u = rem & 15;
        const float* ahw = wp.p[28];
        Wu[gid] = h2u(pk2(ahw[(a*32 + 2*kp)*16 + u], ahw[(a*32 + 2*kp+1)*16 + u]));
    } else {                               // f32 tail
        int i = gid - F32B;
        float v;
        if      (i < 32)   v = wp.p[1][i] * QSCL;          // bq (pre-scaled)
        else if (i < 96)   v = wp.p[3][i - 32];            // bkv
        else if (i < 112)  v = wp.p[5][i - 96];            // bo
        else if (i < 128)  v = wp.p[6][i - 112];           // ln1_g
        else if (i < 144)  v = wp.p[7][i - 128];           // ln1_b
        else if (i < 176)  v = wp.p[9][i - 144];           // il_b
        else if (i < 272)  v = wp.p[12][i - 176];          // gru_bih
        else if (i < 368)  v = wp.p[13][i - 272];          // gru_bhh
        else if (i < 400)  v = wp.p[15][i - 368];          // ms_b
        else if (i < 2448) v = wp.p[17][i - 400];          // mg_b
        else if (i < 3472) { int j = i - 2448; v = wp.p[20][(j >> 5)*64 + 32 + (j & 31)]; } // ma_wkv V
        else if (i < 3504) v = wp.p[21][32 + (i - 3472)];  // ma_bkv V
        else if (i < 4528) v = wp.p[22][i - 3504];         // ma_wo
        else if (i < 4560) v = wp.p[23][i - 4528];         // ma_bo
        else if (i < 4592) v = wp.p[24][i - 4560];         // ln2_g
        else if (i < 4624) v = wp.p[25][i - 4592];         // ln2_b
        else if (i < 4656) v = wp.p[27][i - 4624];         // qs_b
        else               v = wp.p[29][i - 4656];         // ah_b
        W[gid] = v;
    }
}

// K1: per wave = 2 agents. lane = (sub<<5)|t ; t = link/row index.
// LDS = exactly 32 KB (KbH 16K + VbH 16K) -> 5 blocks/CU. The four small f32
// arrays (enc/h/hn/memb) overlay VbH's first 4 KB (dead after P2); aft rows
// overlay KbH. A __syncthreads after P2 is REQUIRED: the overlay region is
// group 0/1's K/V data, so all waves must finish P2 before any overlay write.
// (256,3): proven non-spilling 76-VGPR codegen (<=102 needed for 5 blocks).
__global__ __launch_bounds__(256, 3) void k_main(
    const float* __restrict__ states, const float* __restrict__ hidden,
    const float* W, float* __restrict__ msum, float* __restrict__ outp)
{
    const u32* Wu = (const u32*)W;

    __shared__ uint4 KbH[8][32][4];   // f16 K rows (swizzled); later: aft rows
    __shared__ uint4 VbH[8][32][4];   // f16 V rows (swizzled); later: enc/h/hn/memb
    float* const ovl   = (float*)VbH; // 4096 floats; we use the first 1024
    float* const encB  = ovl;         // [8][32]
    float* const hB    = ovl + 256;   // [8][32]
    float* const hnB   = ovl + 512;   // [8][32]
    float* const membB = ovl + 768;   // [8][32]

    const int w    = threadIdx.x >> 6;
    const int lane = threadIdx.x & 63;
    const int sub  = lane >> 5;
    const int t    = lane & 31;
    const int ag   = w * 2 + sub;
    const int pair = blockIdx.x * 4 + w;
    const int b    = pair >> 5;
    const int a    = ((pair & 31) << 1) | sub;
    const int ba   = b * 64 + a;

    // ---- P0: states row (link t): 16 f32; hidden value (latency overlap) ----
    float s[16];
    {
        const float4* p4 = reinterpret_cast<const float4*>(states + ((size_t)ba * 32 + t) * 16);
        float4 f0 = p4[0], f1 = p4[1], f2 = p4[2], f3 = p4[3];
        s[0]=f0.x; s[1]=f0.y; s[2]=f0.z; s[3]=f0.w;
        s[4]=f1.x; s[5]=f1.y; s[6]=f1.z; s[7]=f1.w;
        s[8]=f2.x; s[9]=f2.y; s[10]=f2.z; s[11]=f2.w;
        s[12]=f3.x; s[13]=f3.y; s[14]=f3.z; s[15]=f3.w;
    }
    float hp = hidden[(size_t)ba * 32 + t];
    h2 sh[8];
    #pragma unroll
    for (int i = 0; i < 8; ++i) sh[i] = pk2(s[2*i], s[2*i+1]);

    // ---- P1a: Q (pre-scaled weights; scores land in exp2 domain) ----
    h2 qh[16];
    #pragma unroll
    for (int j = 0; j < 16; ++j) {
        float a0 = W[BQ + 2*j], a1 = W[BQ + 2*j + 1];
        #pragma unroll
        for (int i = 0; i < 8; ++i) {
            a0 = FD(sh[i], u2h(Wu[QP + (2*j)*8 + i]), a0);
            a1 = FD(sh[i], u2h(Wu[QP + (2*j+1)*8 + i]), a1);
        }
        qh[j] = pk2(a0, a1);
    }
    // ---- P1b: K,V rows -> f16 LDS (swizzled cols) ----
    #pragma unroll
    for (int u = 0; u < 4; ++u) {
        u32 kc[4], vc[4];
        #pragma unroll
        for (int c = 0; c < 4; ++c) {
            int e0 = u*8 + 2*c, e1 = e0 + 1;
            float k0 = W[BKV+e0], k1 = W[BKV+e1];
            float v0 = W[BKV+32+e0], v1 = W[BKV+32+e1];
            #pragma unroll
            for (int i = 0; i < 8; ++i) {
                k0 = FD(sh[i], u2h(Wu[KVP + e0*8 + i]), k0);
                k1 = FD(sh[i], u2h(Wu[KVP + e1*8 + i]), k1);
                v0 = FD(sh[i], u2h(Wu[KVP + (32+e0)*8 + i]), v0);
                v1 = FD(sh[i], u2h(Wu[KVP + (32+e1)*8 + i]), v1);
            }
            kc[c] = h2u(pk2(k0, k1)); vc[c] = h2u(pk2(v0, v1));
        }
        int uc = u ^ (t & 3);
        KbH[ag][t][uc] = make_uint4(kc[0], kc[1], kc[2], kc[3]);
        VbH[ag][t][uc] = make_uint4(vc[0], vc[1], vc[2], vc[3]);
    }
    __syncthreads();

    // ---- P2: 4-head attention, single pass: ov += e*V, l += e; divide once.
    //          e = exp2(sc) -- scale*log2e folded into Q weights ----
    h2 oh[16];
    #pragma unroll
    for (int hh = 0; hh < 4; ++hh) {
        float l0 = 0.0f, l1 = 0.0f;
        h2 ov0 = {(f16)0, (f16)0}, ov1 = ov0, ov2 = ov0, ov3 = ov0;
        #pragma unroll
        for (int k = 0; k < 32; ++k) {
            uint4 kr = KbH[ag][k][hh ^ (k & 3)];   // uniform addr -> broadcast
            float sc = 0.0f;
            sc = FD(qh[hh*4+0], u2h(kr.x), sc);
            sc = FD(qh[hh*4+1], u2h(kr.y), sc);
            sc = FD(qh[hh*4+2], u2h(kr.z), sc);
            sc = FD(qh[hh*4+3], u2h(kr.w), sc);
            float e = EXP2(sc);
            if (k & 1) l1 += e; else l0 += e;
            h2 ph = pk2(e, e);
            uint4 vr = VbH[ag][k][hh ^ (k & 3)];
            ov0 += ph * u2h(vr.x);
            ov1 += ph * u2h(vr.y);
            ov2 += ph * u2h(vr.z);
            ov3 += ph * u2h(vr.w);
        }
        float inv = 1.0f / (l0 + l1);
        h2 hinv = pk2(inv, inv);
        oh[hh*4+0] = ov0 * hinv; oh[hh*4+1] = ov1 * hinv;
        oh[hh*4+2] = ov2 * hinv; oh[hh*4+3] = ov3 * hinv;
    }
    __syncthreads();   // REQUIRED: overlay region below is other groups' K/V

    // ---- P3: out proj + residual + LayerNorm(16) ----
    float aft[16];
    {
        float x[16];
        float mean = 0.0f;
        #pragma unroll
        for (int f = 0; f < 16; ++f) {
            float acc = W[BO + f];
            #pragma unroll
            for (int i = 0; i < 16; ++i) acc = FD(oh[i], u2h(Wu[WOP + f*16 + i]), acc);
            x[f] = s[f] + acc;
            mean += x[f];
        }
        mean *= (1.0f / 16.0f);
        float var = 0.0f;
        #pragma unroll
        for (int f = 0; f < 16; ++f) { float d = x[f] - mean; var += d * d; }
        var *= (1.0f / 16.0f);
        float rs = rsqrtf(var + 1e-5f);
        #pragma unroll
        for (int f = 0; f < 16; ++f)
            aft[f] = (x[f] - mean) * rs * W[LN1G + f] + W[LN1B + f];
    }
    // aft rows -> LDS, overlaying KbH[ag] (dead after P2)
    uint4* aftA = &KbH[ag][0][0];   // 64 uint4 per ag-group
    {
        u32 ac[8];
        #pragma unroll
        for (int c = 0; c < 8; ++c) ac[c] = h2u(pk2(aft[2*c], aft[2*c+1]));
        aftA[2*t]     = make_uint4(ac[0], ac[1], ac[2], ac[3]);
        aftA[2*t + 1] = make_uint4(ac[4], ac[5], ac[6], ac[7]);
    }
    hB[ag*32 + t] = hp;
    __syncthreads();

    // ---- P4: enc[t] = il_b[t] + aft_flat . il_w[:,t]  (f16 dot2) ----
    float enc = W[ILB + t];
    {
        const uint4* aA   = aftA;
        const uint4* ilw4 = (const uint4*)(Wu + ILWP);
        #pragma unroll 8
        for (int jp4 = 0; jp4 < 64; ++jp4) {
            uint4 av = aA[jp4];
            uint4 wv = ilw4[jp4 * 32 + t];
            enc = FD(u2h(av.x), u2h(wv.x), enc);
            enc = FD(u2h(av.y), u2h(wv.y), enc);
            enc = FD(u2h(av.z), u2h(wv.z), enc);
            enc = FD(u2h(av.w), u2h(wv.w), enc);
        }
    }
    encB[ag*32 + t] = enc;
    __syncthreads();

    // ---- P5: GRU ----
    float gi0 = W[BIH + t], gi1 = W[BIH + 32 + t], gi2 = W[BIH + 64 + t];
    float gh0 = W[BHH + t], gh1 = W[BHH + 32 + t], gh2 = W[BHH + 64 + t];
    {
        const float4* eF = (const float4*)(encB + ag*32);
        const float4* hF = (const float4*)(hB + ag*32);
        const uint4* wi4 = (const uint4*)(Wu + WIHP);
        const uint4* wh4 = (const uint4*)(Wu + WHHP);
        #pragma unroll
        for (int q4 = 0; q4 < 8; ++q4) {
            float4 ev = eF[q4], hv = hF[q4];
            h2 ea = pk2(ev.x, ev.y), eb = pk2(ev.z, ev.w);
            h2 ha = pk2(hv.x, hv.y), hb = pk2(hv.z, hv.w);
            uint4 wiA = wi4[(q4*2)*32 + t], wiB = wi4[(q4*2+1)*32 + t];
            uint4 whA = wh4[(q4*2)*32 + t], whB = wh4[(q4*2+1)*32 + t];
            gi0 = FD(ea, u2h(wiA.x), gi0); gi1 = FD(ea, u2h(wiA.y), gi1); gi2 = FD(ea, u2h(wiA.z), gi2);
            gi0 = FD(eb, u2h(wiB.x), gi0); gi1 = FD(eb, u2h(wiB.y), gi1); gi2 = FD(eb, u2h(wiB.z), gi2);
            gh0 = FD(ha, u2h(whA.x), gh0); gh1 = FD(ha, u2h(whA.y), gh1); gh2 = FD(ha, u2h(whA.z), gh2);
            gh0 = FD(hb, u2h(whB.x), gh0); gh1 = FD(hb, u2h(whB.y), gh1); gh2 = FD(hb, u2h(whB.z), gh2);
        }
    }
    float r  = sigm(gi0 + gh0);
    float z  = sigm(gi1 + gh1);
    float n  = tanhf(gi2 + r * gh2);
    float hn = (1.0f - z) * n + z * hp;
    outp[OUT_H + (size_t)ba * 32 + t] = hn;
    hnB[ag*32 + t] = hn;
    __syncthreads();

    // ---- P6: memb = relu(h @ ms_w + b); msg = memb @ mg_w[a] + b;
    //          accumulate batch-mean numerator via device atomics ----
    {
        const float4* nF = (const float4*)(hnB + ag*32);
        float mb = W[MSB + t];
        #pragma unroll
        for (int q4 = 0; q4 < 8; ++q4) {
            float4 v = nF[q4];
            h2 a2 = pk2(v.x, v.y), b2 = pk2(v.z, v.w);
            mb = FD(a2, u2h(Wu[MSWP + (q4*2)*32 + t]), mb);
            mb = FD(b2, u2h(Wu[MSWP + (q4*2+1)*32 + t]), mb);
        }
        mb = fmaxf(mb, 0.0f);
        membB[ag*32 + t] = mb;
    }
    __syncthreads();
    {
        const float4* mF = (const float4*)(membB + ag*32);
        float mg = W[MGB + a * 32 + t];
        #pragma unroll
        for (int q4 = 0; q4 < 8; ++q4) {
            float4 v = mF[q4];
            h2 a2 = pk2(v.x, v.y), b2 = pk2(v.z, v.w);
            mg = FD(a2, u2h(Wu[MGWP + a*512 + (q4*2)*32 + t]), mg);
            mg = FD(b2, u2h(Wu[MGWP + a*512 + (q4*2+1)*32 + t]), mg);
        }
        atomicAdd(&msum[b * 32 + t], mg);
    }
}

// K2: mm = msum/64 -> write OUT_MM broadcast; inline degenerate comm-attn
// (sl=1 => softmax==1 => ao = (mm @ wkv_V + bkv_V) @ wo + bo, per batch);
// LN2(h+ao) -> feat=[h,after] -> relu(qs) -> per-agent Q head.
__global__ __launch_bounds__(256) void k_tail(
    const float* __restrict__ msum, const float* W, float* __restrict__ outp)
{
    const u32* Wu = (const u32*)W;
    __shared__ __align__(16) float mmS[8][32];
    __shared__ __align__(16) float vS[8][32];
    __shared__ __align__(16) float featS[8][64];
    __shared__ __align__(16) float qeS[8][32];
    const int w    = threadIdx.x >> 6;
    const int lane = threadIdx.x & 63;
    const int sub  = lane >> 5;
    const int t    = lane & 31;
    const int ag   = w * 2 + sub;
    const int pair = blockIdx.x * 4 + w;
    const int b    = pair >> 5;
    const int a    = ((pair & 31) << 1) | sub;
    const int ba   = b * 64 + a;

    float h  = outp[OUT_H + (size_t)ba * 32 + t];
    float mm = msum[b * 32 + t] * 0.015625f;    // /64
    outp[OUT_MM + (size_t)ba * 32 + t] = mm;
    mmS[ag][t] = mm;
    __syncthreads();
    float v = W[MABKVV + t];
    for (int k = 0; k < 32; ++k) v += mmS[ag][k] * W[MAWKVV + k * 32 + t];
    vS[ag][t] = v;
    __syncthreads();
    float ao = W[MABO + t];
    for (int k = 0; k < 32; ++k) ao += vS[ag][k] * W[MAWO + k * 32 + t];

    float x  = h + ao;
    float sm = x;
    #pragma unroll
    for (int m2 = 1; m2 < 32; m2 <<= 1) sm += __shfl_xor(sm, m2, 64);
    float mean = sm * (1.0f / 32.0f);
    float dx = x - mean;
    float vv = dx * dx;
    #pragma unroll
    for (int m2 = 1; m2 < 32; m2 <<= 1) vv += __shfl_xor(vv, m2, 64);
    float var   = vv * (1.0f / 32.0f);
    float after = dx * rsqrtf(var + 1e-5f) * W[LN2G + t] + W[LN2B + t];

    featS[ag][t]      = h;
    featS[ag][32 + t] = after;
    __syncthreads();
    {
        const float4* fF = (const float4*)&featS[ag][0];
        float acc = W[QSB + t];
        #pragma unroll
        for (int q4 = 0; q4 < 16; ++q4) {
            float4 fv = fF[q4];
            h2 a2 = pk2(fv.x, fv.y), b2 = pk2(fv.z, fv.w);
            acc = FD(a2, u2h(Wu[QSWP + (q4*2)*32 + t]), acc);
            acc = FD(b2, u2h(Wu[QSWP + (q4*2+1)*32 + t]), acc);
        }
        acc = fmaxf(acc, 0.0f);
        qeS[ag][t] = acc;
    }
    __syncthreads();
    if (t < 16) {
        const float4* qF = (const float4*)&qeS[ag][0];
        float qa = W[AHB + a * 16 + t];
        #pragma unroll
        for (int q4 = 0; q4 < 8; ++q4) {
            float4 qv = qF[q4];
            h2 a2 = pk2(qv.x, qv.y), b2 = pk2(qv.z, qv.w);
            qa = FD(a2, u2h(Wu[AHWP + a*256 + (q4*2)*16 + t]), qa);
            qa = FD(b2, u2h(Wu[AHWP + a*256 + (q4*2+1)*16 + t]), qa);
        }
        outp[OUT_Q + (size_t)ba * 16 + t] = qa;
    }
}

extern "C" void kernel_launch(void* const* d_in, const int* in_sizes, int n_in,
                              void* d_out, int out_size, void* d_ws, size_t ws_size,
                              hipStream_t stream) {
    (void)in_sizes; (void)n_in; (void)out_size; (void)ws_size;
    WP wp;
    for (int i = 0; i < 30; ++i) wp.p[i] = (const float*)d_in[i + 2];

    float* W    = (float*)d_ws;
    float* msum = W + W_ALLOC;   // 1024*32 f32, zeroed by kw_conv each call

    const float* states = (const float*)d_in[0];
    const float* hidden = (const float*)d_in[1];
    float* outp = (float*)d_out;

    kw_conv<<<dim3((W_TOTAL + 255) / 256), dim3(256), 0, stream>>>(wp, W, msum);
    k_main<<<dim3(8192), dim3(256), 0, stream>>>(states, hidden, W, msum, outp);
    k_tail<<<dim3(8192), dim3(256), 0, stream>>>(msum, W, outp);
}

// Round 9
// 482.408 us; speedup vs baseline: 1.0015x; 1.0002x over previous
//
#include <hip/hip_runtime.h>

typedef unsigned int u32;
typedef _Float16 f16;
typedef f16 h2 __attribute__((ext_vector_type(2)));

// ---------------- packed-weight ws layout (u32/f32 element offsets) ----------
#define QP     0        // [e<32][i<8] half2 pairs over f, PRE-SCALED by 1/sqrt(8)*log2e
#define KVP    256      // [e<64][i<8]
#define WOP    768      // [f<16][i<16] pairs over e
#define ILWP   1024     // [(jp4<64 *32 + t)*4 + i] pairs over j
#define WIHP   9216     // [(kp<16 *32 + t)*4 + j] j<3 used
#define WHHP   11264
#define MSWP   13312    // [kp<16 *32 + t]
#define MGWP   13824    // [a*512 + kp<16 *32 + m]
#define QSWP   46592    // [kp<32 *32 + t]
#define AHWP   47616    // [a*256 + kp<16 *16 + u]
#define F32B   64000
#define BQ     (F32B+0)     // 32  (PRE-SCALED like QP)
#define BKV    (F32B+32)    // 64
#define BO     (F32B+96)    // 16
#define LN1G   (F32B+112)   // 16
#define LN1B   (F32B+128)   // 16
#define ILB    (F32B+144)   // 32
#define BIH    (F32B+176)   // 96
#define BHH    (F32B+272)   // 96
#define MSB    (F32B+368)   // 32
#define MGB    (F32B+400)   // 2048
#define MAWKVV (F32B+2448)  // first 512 words: f16 pairs [kp<16][t<32] over k
#define MABKVV (F32B+3472)  // 32 (f32)
#define MAWO   (F32B+3504)  // first 512 words: f16 pairs [kp<16][t<32] over k
#define MABO   (F32B+4528)  // 32 (f32)
#define LN2G   (F32B+4560)  // 32
#define LN2B   (F32B+4592)  // 32
#define QSB    (F32B+4624)  // 32
#define AHB    (F32B+4656)  // 1024
#define W_TOTAL (F32B+5680)
#define W_ALLOC 69696
#define MSUM_N  32768       // 1024 batches x 32, f32, after W in ws

// Q pre-scale: (1/sqrt(8)) * log2(e)  ->  exp(sc*scale) == exp2(sc')
#define QSCL 0.51006973f

// output element offsets (f32): q_values | h | mean_message
#define OUT_Q  0
#define OUT_H  1048576
#define OUT_MM 3145728

#if __has_builtin(__builtin_amdgcn_fdot2)
__device__ __forceinline__ float FD(h2 a, h2 b, float c) {
    return __builtin_amdgcn_fdot2(a, b, c, false);
}
#else
__device__ __forceinline__ float FD(h2 a, h2 b, float c) {
    return c + (float)a.x * (float)b.x + (float)a.y * (float)b.y;
}
#endif

#if __has_builtin(__builtin_amdgcn_exp2f)
__device__ __forceinline__ float EXP2(float x) { return __builtin_amdgcn_exp2f(x); }
#else
__device__ __forceinline__ float EXP2(float x) { return exp2f(x); }
#endif

#if __has_builtin(__builtin_amdgcn_cvt_pkrtz)
__device__ __forceinline__ h2 pk2(float a, float b) {
    auto r = __builtin_amdgcn_cvt_pkrtz(a, b);   // __fp16 vec2 on this clang
    h2 out;
    __builtin_memcpy(&out, &r, sizeof(out));      // no-op bitcast
    return out;
}
#else
__device__ __forceinline__ h2 pk2(float a, float b) { h2 r; r.x = (f16)a; r.y = (f16)b; return r; }
#endif

__device__ __forceinline__ h2  u2h(u32 x) { union { u32 u; h2 h; } c; c.u = x; return c.h; }
__device__ __forceinline__ u32 h2u(h2 x)  { union { u32 u; h2 h; } c; c.h = x; return c.u; }

__device__ __forceinline__ float sigm(float x) { return 1.0f / (1.0f + __expf(-x)); }

struct WP { const float* p[30]; };

// K0: repack weights (f16 pairs along contraction dim) + f32 tail + zero msum
__global__ void kw_conv(WP wp, float* W, float* msum) {
    u32* Wu = (u32*)W;
    int gid = blockIdx.x * blockDim.x + threadIdx.x;
    if (gid < MSUM_N) msum[gid] = 0.0f;
    if (gid >= W_TOTAL) return;
    if (gid < KVP) {                       // QP: ia_wq [16][32], pre-scaled
        int e = gid >> 3, i = gid & 7;
        const float* wq = wp.p[0];
        Wu[gid] = h2u(pk2(wq[(2*i)*32 + e] * QSCL, wq[(2*i+1)*32 + e] * QSCL));
    } else if (gid < WOP) {                // KVP: ia_wkv [16][64]
        int idx = gid - KVP; int e = idx >> 3, i = idx & 7;
        const float* wkv = wp.p[2];
        Wu[gid] = h2u(pk2(wkv[(2*i)*64 + e], wkv[(2*i+1)*64 + e]));
    } else if (gid < ILWP) {               // WOP: ia_wo [32][16]
        int idx = gid - WOP; int f = idx >> 4, i = idx & 15;
        const float* wo = wp.p[4];
        Wu[gid] = h2u(pk2(wo[(2*i)*16 + f], wo[(2*i+1)*16 + f]));
    } else if (gid < WIHP) {               // ILWP: il_w [512][32]
        int idx = gid - ILWP;
        int jp4 = idx >> 7, t = (idx >> 2) & 31, i = idx & 3;
        int jp = jp4 * 4 + i;
        const float* ilw = wp.p[8];
        Wu[gid] = h2u(pk2(ilw[(2*jp)*32 + t], ilw[(2*jp+1)*32 + t]));
    } else if (gid < WHHP) {               // WIHP: gru_wih [32][96]
        int idx = gid - WIHP;
        int kp = idx >> 7, t = (idx >> 2) & 31, j = idx & 3;
        const float* wih = wp.p[10];
        Wu[gid] = (j < 3) ? h2u(pk2(wih[(2*kp)*96 + j*32 + t], wih[(2*kp+1)*96 + j*32 + t])) : 0u;
    } else if (gid < MSWP) {               // WHHP: gru_whh [32][96]
        int idx = gid - WHHP;
        int kp = idx >> 7, t = (idx >> 2) & 31, j = idx & 3;
        const float* whh = wp.p[11];
        Wu[gid] = (j < 3) ? h2u(pk2(whh[(2*kp)*96 + j*32 + t], whh[(2*kp+1)*96 + j*32 + t])) : 0u;
    } else if (gid < MGWP) {               // MSWP: ms_w [32][32]
        int idx = gid - MSWP; int kp = idx >> 5, t = idx & 31;
        const float* msw = wp.p[14];
        Wu[gid] = h2u(pk2(msw[(2*kp)*32 + t], msw[(2*kp+1)*32 + t]));
    } else if (gid < QSWP) {               // MGWP: mg_w [64][32][32]
        int idx = gid - MGWP; int a = idx >> 9, rem = idx & 511, kp = rem >> 5, m = rem & 31;
        const float* mgw = wp.p[16];
        Wu[gid] = h2u(pk2(mgw[(a*32 + 2*kp)*32 + m], mgw[(a*32 + 2*kp+1)*32 + m]));
    } else if (gid < AHWP) {               // QSWP: qs_w [64][32]
        int idx = gid - QSWP; int kp = idx >> 5, t = idx & 31;
        const float* qsw = wp.p[26];
        Wu[gid] = h2u(pk2(qsw[(2*kp)*32 + t], qsw[(2*kp+1)*32 + t]));
    } else if (gid < F32B) {               // AHWP: ah_w [64][32][16]
        int idx = gid - AHWP; int a = idx >> 8, rem = idx & 255, kp = rem >> 4, u = rem & 15;
        const float* ahw = wp.p[28];
        Wu[gid] = h2u(pk2(ahw[(a*32 + 2*kp)*16 + u], ahw[(a*32 + 2*kp+1)*16 + u]));
    } else {                               // f32 tail (+ two packed f16 GEMV tables)
        int i = gid - F32B;
        if (i >= 2448 && i < 3472) {           // ma_wkv V-half, packed f16 pairs
            int j = i - 2448;
            if (j < 512) {
                int kp = j >> 5, t = j & 31;
                const float* wkv = wp.p[20];
                Wu[gid] = h2u(pk2(wkv[(2*kp)*64 + 32 + t], wkv[(2*kp+1)*64 + 32 + t]));
            } else Wu[gid] = 0u;
            return;
        }
        if (i >= 3504 && i < 4528) {           // ma_wo, packed f16 pairs
            int j = i - 3504;
            if (j < 512) {
                int kp = j >> 5, t = j & 31;
                const float* wo = wp.p[22];
                Wu[gid] = h2u(pk2(wo[(2*kp)*32 + t], wo[(2*kp+1)*32 + t]));
            } else Wu[gid] = 0u;
            return;
        }
        float v;
        if      (i < 32)   v = wp.p[1][i] * QSCL;          // bq (pre-scaled)
        else if (i < 96)   v = wp.p[3][i - 32];            // bkv
        else if (i < 112)  v = wp.p[5][i - 96];            // bo
        else if (i < 128)  v = wp.p[6][i - 112];           // ln1_g
        else if (i < 144)  v = wp.p[7][i - 128];           // ln1_b
        else if (i < 176)  v = wp.p[9][i - 144];           // il_b
        else if (i < 272)  v = wp.p[12][i - 176];          // gru_bih
        else if (i < 368)  v = wp.p[13][i - 272];          // gru_bhh
        else if (i < 400)  v = wp.p[15][i - 368];          // ms_b
        else if (i < 2448) v = wp.p[17][i - 400];          // mg_b
        else if (i < 3504) v = wp.p[21][32 + (i - 3472)];  // ma_bkv V
        else if (i < 4560) v = wp.p[23][i - 4528];         // ma_bo
        else if (i < 4592) v = wp.p[24][i - 4560];         // ln2_g
        else if (i < 4624) v = wp.p[25][i - 4592];         // ln2_b
        else if (i < 4656) v = wp.p[27][i - 4624];         // qs_b
        else               v = wp.p[29][i - 4656];         // ah_b
        W[gid] = v;
    }
}

// K1: per wave = 2 agents. lane = (sub<<5)|t ; t = link/row index.
// LDS = exactly 32 KB -> 5 blocks/CU fit. __launch_bounds__(256,5): for
// 256-thread blocks the 2nd arg == blocks/CU co-residency request; R5-R8
// evidence shows measured occupancy tracks this arg (3->~33%, 4->~43%), so
// request the full 5. VGPR 76 < 512/5 -> no spill expected (verify WRITE_SIZE
// stays ~20 MB). Overlays: aft rows on KbH, enc/h/hn/memb on VbH (both dead
// after P2; barrier after P2 required before overlay writes).
__global__ __launch_bounds__(256, 5) void k_main(
    const float* __restrict__ states, const float* __restrict__ hidden,
    const float* W, float* __restrict__ msum, float* __restrict__ outp)
{
    const u32* Wu = (const u32*)W;

    __shared__ uint4 KbH[8][32][4];   // f16 K rows (swizzled); later: aft rows
    __shared__ uint4 VbH[8][32][4];   // f16 V rows (swizzled); later: enc/h/hn/memb
    float* const ovl   = (float*)VbH; // 4096 floats; we use the first 1024
    float* const encB  = ovl;         // [8][32]
    float* const hB    = ovl + 256;   // [8][32]
    float* const hnB   = ovl + 512;   // [8][32]
    float* const membB = ovl + 768;   // [8][32]

    const int w    = threadIdx.x >> 6;
    const int lane = threadIdx.x & 63;
    const int sub  = lane >> 5;
    const int t    = lane & 31;
    const int ag   = w * 2 + sub;
    const int pair = blockIdx.x * 4 + w;
    const int b    = pair >> 5;
    const int a    = ((pair & 31) << 1) | sub;
    const int ba   = b * 64 + a;

    // ---- P0: states row (link t): 16 f32; hidden value (latency overlap) ----
    float s[16];
    {
        const float4* p4 = reinterpret_cast<const float4*>(states + ((size_t)ba * 32 + t) * 16);
        float4 f0 = p4[0], f1 = p4[1], f2 = p4[2], f3 = p4[3];
        s[0]=f0.x; s[1]=f0.y; s[2]=f0.z; s[3]=f0.w;
        s[4]=f1.x; s[5]=f1.y; s[6]=f1.z; s[7]=f1.w;
        s[8]=f2.x; s[9]=f2.y; s[10]=f2.z; s[11]=f2.w;
        s[12]=f3.x; s[13]=f3.y; s[14]=f3.z; s[15]=f3.w;
    }
    float hp = hidden[(size_t)ba * 32 + t];
    h2 sh[8];
    #pragma unroll
    for (int i = 0; i < 8; ++i) sh[i] = pk2(s[2*i], s[2*i+1]);

    // ---- P1a: Q (pre-scaled weights; scores land in exp2 domain) ----
    h2 qh[16];
    #pragma unroll
    for (int j = 0; j < 16; ++j) {
        float a0 = W[BQ + 2*j], a1 = W[BQ + 2*j + 1];
        #pragma unroll
        for (int i = 0; i < 8; ++i) {
            a0 = FD(sh[i], u2h(Wu[QP + (2*j)*8 + i]), a0);
            a1 = FD(sh[i], u2h(Wu[QP + (2*j+1)*8 + i]), a1);
        }
        qh[j] = pk2(a0, a1);
    }
    // ---- P1b: K,V rows -> f16 LDS (swizzled cols) ----
    #pragma unroll
    for (int u = 0; u < 4; ++u) {
        u32 kc[4], vc[4];
        #pragma unroll
        for (int c = 0; c < 4; ++c) {
            int e0 = u*8 + 2*c, e1 = e0 + 1;
            float k0 = W[BKV+e0], k1 = W[BKV+e1];
            float v0 = W[BKV+32+e0], v1 = W[BKV+32+e1];
            #pragma unroll
            for (int i = 0; i < 8; ++i) {
                k0 = FD(sh[i], u2h(Wu[KVP + e0*8 + i]), k0);
                k1 = FD(sh[i], u2h(Wu[KVP + e1*8 + i]), k1);
                v0 = FD(sh[i], u2h(Wu[KVP + (32+e0)*8 + i]), v0);
                v1 = FD(sh[i], u2h(Wu[KVP + (32+e1)*8 + i]), v1);
            }
            kc[c] = h2u(pk2(k0, k1)); vc[c] = h2u(pk2(v0, v1));
        }
        int uc = u ^ (t & 3);
        KbH[ag][t][uc] = make_uint4(kc[0], kc[1], kc[2], kc[3]);
        VbH[ag][t][uc] = make_uint4(vc[0], vc[1], vc[2], vc[3]);
    }
    __syncthreads();

    // ---- P2: 4-head attention, single pass: ov += e*V, l += e; divide once.
    //          e = exp2(sc) -- scale*log2e folded into Q weights ----
    h2 oh[16];
    #pragma unroll
    for (int hh = 0; hh < 4; ++hh) {
        float l0 = 0.0f, l1 = 0.0f;
        h2 ov0 = {(f16)0, (f16)0}, ov1 = ov0, ov2 = ov0, ov3 = ov0;
        #pragma unroll
        for (int k = 0; k < 32; ++k) {
            uint4 kr = KbH[ag][k][hh ^ (k & 3)];   // uniform addr -> broadcast
            float sc = 0.0f;
            sc = FD(qh[hh*4+0], u2h(kr.x), sc);
            sc = FD(qh[hh*4+1], u2h(kr.y), sc);
            sc = FD(qh[hh*4+2], u2h(kr.z), sc);
            sc = FD(qh[hh*4+3], u2h(kr.w), sc);
            float e = EXP2(sc);
            if (k & 1) l1 += e; else l0 += e;
            h2 ph = pk2(e, e);
            uint4 vr = VbH[ag][k][hh ^ (k & 3)];
            ov0 += ph * u2h(vr.x);
            ov1 += ph * u2h(vr.y);
            ov2 += ph * u2h(vr.z);
            ov3 += ph * u2h(vr.w);
        }
        float inv = 1.0f / (l0 + l1);
        h2 hinv = pk2(inv, inv);
        oh[hh*4+0] = ov0 * hinv; oh[hh*4+1] = ov1 * hinv;
        oh[hh*4+2] = ov2 * hinv; oh[hh*4+3] = ov3 * hinv;
    }
    __syncthreads();   // REQUIRED: overlay region below is other groups' K/V

    // ---- P3: out proj + residual + LayerNorm(16) ----
    float aft[16];
    {
        float x[16];
        float mean = 0.0f;
        #pragma unroll
        for (int f = 0; f < 16; ++f) {
            float acc = W[BO + f];
            #pragma unroll
            for (int i = 0; i < 16; ++i) acc = FD(oh[i], u2h(Wu[WOP + f*16 + i]), acc);
            x[f] = s[f] + acc;
            mean += x[f];
        }
        mean *= (1.0f / 16.0f);
        float var = 0.0f;
        #pragma unroll
        for (int f = 0; f < 16; ++f) { float d = x[f] - mean; var += d * d; }
        var *= (1.0f / 16.0f);
        float rs = rsqrtf(var + 1e-5f);
        #pragma unroll
        for (int f = 0; f < 16; ++f)
            aft[f] = (x[f] - mean) * rs * W[LN1G + f] + W[LN1B + f];
    }
    // aft rows -> LDS, overlaying KbH[ag] (dead after P2)
    uint4* aftA = &KbH[ag][0][0];   // 64 uint4 per ag-group
    {
        u32 ac[8];
        #pragma unroll
        for (int c = 0; c < 8; ++c) ac[c] = h2u(pk2(aft[2*c], aft[2*c+1]));
        aftA[2*t]     = make_uint4(ac[0], ac[1], ac[2], ac[3]);
        aftA[2*t + 1] = make_uint4(ac[4], ac[5], ac[6], ac[7]);
    }
    hB[ag*32 + t] = hp;
    __syncthreads();

    // ---- P4: enc[t] = il_b[t] + aft_flat . il_w[:,t]  (f16 dot2) ----
    float enc = W[ILB + t];
    {
        const uint4* aA   = aftA;
        const uint4* ilw4 = (const uint4*)(Wu + ILWP);
        #pragma unroll 8
        for (int jp4 = 0; jp4 < 64; ++jp4) {
            uint4 av = aA[jp4];
            uint4 wv = ilw4[jp4 * 32 + t];
            enc = FD(u2h(av.x), u2h(wv.x), enc);
            enc = FD(u2h(av.y), u2h(wv.y), enc);
            enc = FD(u2h(av.z), u2h(wv.z), enc);
            enc = FD(u2h(av.w), u2h(wv.w), enc);
        }
    }
    encB[ag*32 + t] = enc;
    __syncthreads();

    // ---- P5: GRU ----
    float gi0 = W[BIH + t], gi1 = W[BIH + 32 + t], gi2 = W[BIH + 64 + t];
    float gh0 = W[BHH + t], gh1 = W[BHH + 32 + t], gh2 = W[BHH + 64 + t];
    {
        const float4* eF = (const float4*)(encB + ag*32);
        const float4* hF = (const float4*)(hB + ag*32);
        const uint4* wi4 = (const uint4*)(Wu + WIHP);
        const uint4* wh4 = (const uint4*)(Wu + WHHP);
        #pragma unroll
        for (int q4 = 0; q4 < 8; ++q4) {
            float4 ev = eF[q4], hv = hF[q4];
            h2 ea = pk2(ev.x, ev.y), eb = pk2(ev.z, ev.w);
            h2 ha = pk2(hv.x, hv.y), hb = pk2(hv.z, hv.w);
            uint4 wiA = wi4[(q4*2)*32 + t], wiB = wi4[(q4*2+1)*32 + t];
            uint4 whA = wh4[(q4*2)*32 + t], whB = wh4[(q4*2+1)*32 + t];
            gi0 = FD(ea, u2h(wiA.x), gi0); gi1 = FD(ea, u2h(wiA.y), gi1); gi2 = FD(ea, u2h(wiA.z), gi2);
            gi0 = FD(eb, u2h(wiB.x), gi0); gi1 = FD(eb, u2h(wiB.y), gi1); gi2 = FD(eb, u2h(wiB.z), gi2);
            gh0 = FD(ha, u2h(whA.x), gh0); gh1 = FD(ha, u2h(whA.y), gh1); gh2 = FD(ha, u2h(whA.z), gh2);
            gh0 = FD(hb, u2h(whB.x), gh0); gh1 = FD(hb, u2h(whB.y), gh1); gh2 = FD(hb, u2h(whB.z), gh2);
        }
    }
    float r  = sigm(gi0 + gh0);
    float z  = sigm(gi1 + gh1);
    float n  = tanhf(gi2 + r * gh2);
    float hn = (1.0f - z) * n + z * hp;
    outp[OUT_H + (size_t)ba * 32 + t] = hn;
    hnB[ag*32 + t] = hn;
    __syncthreads();

    // ---- P6: memb = relu(h @ ms_w + b); msg = memb @ mg_w[a] + b;
    //          accumulate batch-mean numerator via device atomics ----
    {
        const float4* nF = (const float4*)(hnB + ag*32);
        float mb = W[MSB + t];
        #pragma unroll
        for (int q4 = 0; q4 < 8; ++q4) {
            float4 v = nF[q4];
            h2 a2 = pk2(v.x, v.y), b2 = pk2(v.z, v.w);
            mb = FD(a2, u2h(Wu[MSWP + (q4*2)*32 + t]), mb);
            mb = FD(b2, u2h(Wu[MSWP + (q4*2+1)*32 + t]), mb);
        }
        mb = fmaxf(mb, 0.0f);
        membB[ag*32 + t] = mb;
    }
    __syncthreads();
    {
        const float4* mF = (const float4*)(membB + ag*32);
        float mg = W[MGB + a * 32 + t];
        #pragma unroll
        for (int q4 = 0; q4 < 8; ++q4) {
            float4 v = mF[q4];
            h2 a2 = pk2(v.x, v.y), b2 = pk2(v.z, v.w);
            mg = FD(a2, u2h(Wu[MGWP + a*512 + (q4*2)*32 + t]), mg);
            mg = FD(b2, u2h(Wu[MGWP + a*512 + (q4*2+1)*32 + t]), mg);
        }
        atomicAdd(&msum[b * 32 + t], mg);
    }
}

// K2: mm = msum/64 -> write OUT_MM broadcast; inline degenerate comm-attn
// (sl=1 => softmax==1 => ao = (mm @ wkv_V + bkv_V) @ wo + bo, per batch);
// LN2(h+ao) -> feat=[h,after] -> relu(qs) -> per-agent Q head.
// Comm-attn GEMVs use packed f16 pairs (16-deep dot2 chains vs 32-deep f32).
__global__ __launch_bounds__(256) void k_tail(
    const float* __restrict__ msum, const float* __restrict__ W,
    float* __restrict__ outp)
{
    const u32* Wu = (const u32*)W;
    __shared__ __align__(16) float mmS[8][32];
    __shared__ __align__(16) float vS[8][32];
    __shared__ __align__(16) float featS[8][64];
    __shared__ __align__(16) float qeS[8][32];
    const int w    = threadIdx.x >> 6;
    const int lane = threadIdx.x & 63;
    const int sub  = lane >> 5;
    const int t    = lane & 31;
    const int ag   = w * 2 + sub;
    const int pair = blockIdx.x * 4 + w;
    const int b    = pair >> 5;
    const int a    = ((pair & 31) << 1) | sub;
    const int ba   = b * 64 + a;

    float h  = outp[OUT_H + (size_t)ba * 32 + t];
    float mm = msum[b * 32 + t] * 0.015625f;    // /64
    outp[OUT_MM + (size_t)ba * 32 + t] = mm;
    mmS[ag][t] = mm;
    __syncthreads();
    {
        const float4* mF = (const float4*)&mmS[ag][0];
        float v = W[MABKVV + t];
        #pragma unroll
        for (int q4 = 0; q4 < 4; ++q4) {
            float4 fv = mF[q4];
            h2 a2 = pk2(fv.x, fv.y), b2 = pk2(fv.z, fv.w);
            v = FD(a2, u2h(Wu[MAWKVV + (q4*2)*32 + t]), v);
            v = FD(b2, u2h(Wu[MAWKVV + (q4*2+1)*32 + t]), v);
        }
        vS[ag][t] = v;
    }
    __syncthreads();
    float ao = W[MABO + t];
    {
        const float4* vF = (const float4*)&vS[ag][0];
        #pragma unroll
        for (int q4 = 0; q4 < 4; ++q4) {
            float4 fv = vF[q4];
            h2 a2 = pk2(fv.x, fv.y), b2 = pk2(fv.z, fv.w);
            ao = FD(a2, u2h(Wu[MAWO + (q4*2)*32 + t]), ao);
            ao = FD(b2, u2h(Wu[MAWO + (q4*2+1)*32 + t]), ao);
        }
    }

    float x  = h + ao;
    float sm = x;
    #pragma unroll
    for (int m2 = 1; m2 < 32; m2 <<= 1) sm += __shfl_xor(sm, m2, 64);
    float mean = sm * (1.0f / 32.0f);
    float dx = x - mean;
    float vv = dx * dx;
    #pragma unroll
    for (int m2 = 1; m2 < 32; m2 <<= 1) vv += __shfl_xor(vv, m2, 64);
    float var   = vv * (1.0f / 32.0f);
    float after = dx * rsqrtf(var + 1e-5f) * W[LN2G + t] + W[LN2B + t];

    featS[ag][t]      = h;
    featS[ag][32 + t] = after;
    __syncthreads();
    {
        const float4* fF = (const float4*)&featS[ag][0];
        float acc = W[QSB + t];
        #pragma unroll
        for (int q4 = 0; q4 < 16; ++q4) {
            float4 fv = fF[q4];
            h2 a2 = pk2(fv.x, fv.y), b2 = pk2(fv.z, fv.w);
            acc = FD(a2, u2h(Wu[QSWP + (q4*2)*32 + t]), acc);
            acc = FD(b2, u2h(Wu[QSWP + (q4*2+1)*32 + t]), acc);
        }
        acc = fmaxf(acc, 0.0f);
        qeS[ag][t] = acc;
    }
    __syncthreads();
    if (t < 16) {
        const float4* qF = (const float4*)&qeS[ag][0];
        float qa = W[AHB + a * 16 + t];
        #pragma unroll
        for (int q4 = 0; q4 < 8; ++q4) {
            float4 qv = qF[q4];
            h2 a2 = pk2(qv.x, qv.y), b2 = pk2(qv.z, qv.w);
            qa = FD(a2, u2h(Wu[AHWP + a*256 + (q4*2)*16 + t]), qa);
            qa = FD(b2, u2h(Wu[AHWP + a*256 + (q4*2+1)*16 + t]), qa);
        }
        outp[OUT_Q + (size_t)ba * 16 + t] = qa;
    }
}

extern "C" void kernel_launch(void* const* d_in, const int* in_sizes, int n_in,
                              void* d_out, int out_size, void* d_ws, size_t ws_size,
                              hipStream_t stream) {
    (void)in_sizes; (void)n_in; (void)out_size; (void)ws_size;
    WP wp;
    for (int i = 0; i < 30; ++i) wp.p[i] = (const float*)d_in[i + 2];

    float* W    = (float*)d_ws;
    float* msum = W + W_ALLOC;   // 1024*32 f32, zeroed by kw_conv each call

    const float* states = (const float*)d_in[0];
    const float* hidden = (const float*)d_in[1];
    float* outp = (float*)d_out;

    kw_conv<<<dim3((W_TOTAL + 255) / 256), dim3(256), 0, stream>>>(wp, W, msum);
    k_main<<<dim3(8192), dim3(256), 0, stream>>>(states, hidden, W, msum, outp);
    k_tail<<<dim3(8192), dim3(256), 0, stream>>>(msum, W, outp);
}